// Round 2
// baseline (90.926 us; speedup 1.0000x reference)
//
#include <hip/hip_runtime.h>

#define NB 8
#define LC 512
#define LQ 64
#define DD 256
#define NEG_BIG_F 1e30f

#define TPB 256            // 4 waves
#define NWAVE 4
#define RPW 4              // rows per wave: one T-pass feeds 4 rows
#define RPB (NWAVE * RPW)  // 16 rows per block
#define BPB (LC / RPB)     // 32 blocks per batch -> grid = 256 (1 block/CU)
#define CNT_OFF (NB * LC * 16)   // per-batch counters right after ws4 (64 KiB)

// Broadcast a float from `lane` to all lanes as a wave-uniform (SGPR) value.
__device__ __forceinline__ float bcastf(float x, int lane) {
  return __uint_as_float((unsigned)__builtin_amdgcn_readlane((int)__float_as_uint(x), lane));
}

__global__ __launch_bounds__(TPB, 2) void fused_kernel(
    const float* __restrict__ context,   // [NB][LC][DD]
    const float* __restrict__ question,  // [NB][LQ][DD]
    const int*   __restrict__ mask,      // [NB][LQ]
    const float* __restrict__ att_w,     // [3*DD]
    const float* __restrict__ att_b,     // [1]
    const float* __restrict__ w_in,      // [DD]
    const float* __restrict__ w_mem,     // [DD]
    float4* __restrict__ ws4,            // [NB*LC] {rowmax, ctx1, U, 0}
    int*    __restrict__ cnt,            // [NB], zeroed by memset each launch
    float4* __restrict__ out4)           // [NB*LC] {c1, U, c1*U, U*H}
{
  // T[c][j ^ (c&7)] = question[b][j][4c..4c+3].
  // Writes: lane=c (fixed j)  -> 8 distinct 16B slots per 128B phase.
  // Reads : lane=j (fixed c)  -> blockwise-XOR perm of consecutive float4s.
  // Both conflict-free.
  __shared__ float4 T[64][64];                   // 64 KiB
  __shared__ float sq_raw[LQ];
  __shared__ float q1_s[LQ];
  __shared__ float rr[3][NWAVE];                 // tail cross-wave scratch
  __shared__ int   lastv;

  const int tid  = threadIdx.x;
  const int w    = tid >> 6;           // wave 0..3
  const int l    = tid & 63;           // lane
  const int b    = blockIdx.x / BPB;
  const int row0 = (blockIdx.x % BPB) * RPB;
  const int i0   = row0 + w * RPW;     // this wave's first context row

  // ---- hoisted per-lane loads (lane = d-chunk) ----
  const float4 wc4 = ((const float4*)att_w)[l];
  const float4 wq4 = ((const float4*)(att_w + DD))[l];
  const float4 wp4 = ((const float4*)(att_w + 2 * DD))[l];
  const float4 wi4 = ((const float4*)w_in)[l];
  const float4 wm4 = ((const float4*)w_mem)[l];

  float4 c4[RPW];
#pragma unroll
  for (int r = 0; r < RPW; ++r)
    c4[r] = ((const float4*)(context + ((size_t)b * LC + (i0 + r)) * DD))[l];

  // ---- staging: two passes of 8 row-loads (bounds VGPR pressure).
  // Instruction k loads q-row j = (pass*8+k)*4 + w: 64 lanes x 16B = 1 KiB row.
  float psq[16], pq1[16];
#pragma unroll
  for (int pass = 0; pass < 2; ++pass) {
    float4 v[8];
#pragma unroll
    for (int k = 0; k < 8; ++k) {
      const int j = (pass * 8 + k) * NWAVE + w;
      v[k] = ((const float4*)(question + ((size_t)b * LQ + j) * DD))[l];
    }
#pragma unroll
    for (int k = 0; k < 8; ++k) {
      const int j = (pass * 8 + k) * NWAVE + w;
      T[l][j ^ (l & 7)] = v[k];
    }
#pragma unroll
    for (int k = 0; k < 8; ++k) {
      psq[pass * 8 + k] = v[k].x*wq4.x + v[k].y*wq4.y + v[k].z*wq4.z + v[k].w*wq4.w;
      pq1[pass * 8 + k] = v[k].x*wm4.x + v[k].y*wm4.y + v[k].z*wm4.z + v[k].w*wm4.w;
    }
  }
#pragma unroll
  for (int off = 32; off > 0; off >>= 1) {
#pragma unroll
    for (int m = 0; m < 16; ++m) {
      psq[m] += __shfl_xor(psq[m], off);
      pq1[m] += __shfl_xor(pq1[m], off);
    }
  }
  if (l == 0) {
#pragma unroll
    for (int m = 0; m < 16; ++m) {
      sq_raw[m * NWAVE + w] = psq[m];
      q1_s[m * NWAVE + w]   = pq1[m];
    }
  }

  // ---- row-local terms (overlap with staging latency) ----
  float4 cp[RPW]; float sc[RPW], c1[RPW];
#pragma unroll
  for (int r = 0; r < RPW; ++r) {
    cp[r].x = c4[r].x*wp4.x; cp[r].y = c4[r].y*wp4.y;
    cp[r].z = c4[r].z*wp4.z; cp[r].w = c4[r].w*wp4.w;
    sc[r] = c4[r].x*wc4.x + c4[r].y*wc4.y + c4[r].z*wc4.z + c4[r].w*wc4.w;
    c1[r] = c4[r].x*wi4.x + c4[r].y*wi4.y + c4[r].z*wi4.z + c4[r].w*wi4.w;
  }
#pragma unroll
  for (int off = 32; off > 0; off >>= 1) {
#pragma unroll
    for (int r = 0; r < RPW; ++r) {
      sc[r] += __shfl_xor(sc[r], off);
      c1[r] += __shfl_xor(c1[r], off);
    }
  }

  __syncthreads();

  // ---- main loop: lane l = q-column j; ctx chunks broadcast via readlane.
  // ONE T-pass feeds FOUR rows -> per-CU DS traffic halved vs RPW=2.
  float a[RPW][4];
#pragma unroll
  for (int r = 0; r < RPW; ++r) { a[r][0]=a[r][1]=a[r][2]=a[r][3]=0.f; }
#pragma unroll
  for (int c = 0; c < 64; ++c) {
    const float4 qv = T[c][l ^ (c & 7)];
#pragma unroll
    for (int r = 0; r < RPW; ++r) {
      a[r][0] += bcastf(cp[r].x, c) * qv.x;
      a[r][1] += bcastf(cp[r].y, c) * qv.y;
      a[r][2] += bcastf(cp[r].z, c) * qv.z;
      a[r][3] += bcastf(cp[r].w, c) * qv.w;
    }
  }

  const float mf   = (float)mask[b * LQ + l];
  const float base = sq_raw[l] + att_b[0] - NEG_BIG_F * (1.0f - mf);
  const float q1l  = q1_s[l];

  float s[RPW], mr[RPW];
#pragma unroll
  for (int r = 0; r < RPW; ++r) {
    s[r]  = (a[r][0] + a[r][1]) + (a[r][2] + a[r][3]) + sc[r] + base;
    mr[r] = s[r];
  }
#pragma unroll
  for (int off = 32; off > 0; off >>= 1)
#pragma unroll
    for (int r = 0; r < RPW; ++r) mr[r] = fmaxf(mr[r], __shfl_xor(mr[r], off));

  float ps[RPW], pu[RPW];
#pragma unroll
  for (int r = 0; r < RPW; ++r) {
    const float p = __expf(s[r] - mr[r]);
    ps[r] = p; pu[r] = p * q1l;
  }
#pragma unroll
  for (int off = 32; off > 0; off >>= 1) {
#pragma unroll
    for (int r = 0; r < RPW; ++r) {
      ps[r] += __shfl_xor(ps[r], off);
      pu[r] += __shfl_xor(pu[r], off);
    }
  }
  if (l == 0) {
#pragma unroll
    for (int r = 0; r < RPW; ++r)
      ws4[b * LC + i0 + r] = make_float4(mr[r], c1[r], pu[r] / ps[r], 0.f);
  }

  // ---- last-block-done handshake (device-scope; counter memset-zeroed) ----
  __syncthreads();                       // all ws4 stores of this block issued
  if (tid == 0) {
    __threadfence();                     // release: ws4 stores device-visible
    const int old = atomicAdd(&cnt[b], 1);
    lastv = (old == BPB - 1);
    __threadfence();                     // acquire for the tail reads
  }
  __syncthreads();
  if (!lastv) return;

  // ---- batch tail: softmax over row-maxes -> H; write final out ----
  const float4 vA = ws4[b * LC + tid];
  const float4 vB = ws4[b * LC + 256 + tid];
  float mx = fmaxf(vA.x, vB.x);
#pragma unroll
  for (int off = 32; off > 0; off >>= 1) mx = fmaxf(mx, __shfl_xor(mx, off));
  if (l == 0) rr[0][w] = mx;
  __syncthreads();
  mx = fmaxf(fmaxf(rr[0][0], rr[0][1]), fmaxf(rr[0][2], rr[0][3]));

  const float pA = __expf(vA.x - mx), pB = __expf(vB.x - mx);
  float S = pA + pB;
  float C = pA * vA.y + pB * vB.y;
#pragma unroll
  for (int off = 32; off > 0; off >>= 1) {
    S += __shfl_xor(S, off);
    C += __shfl_xor(C, off);
  }
  if (l == 0) { rr[1][w] = S; rr[2][w] = C; }
  __syncthreads();
  S = rr[1][0] + rr[1][1] + rr[1][2] + rr[1][3];
  C = rr[2][0] + rr[2][1] + rr[2][2] + rr[2][3];
  const float H = C / S;

  out4[b * LC + tid]       = make_float4(vA.y, vA.z, vA.y * vA.z, vA.z * H);
  out4[b * LC + 256 + tid] = make_float4(vB.y, vB.z, vB.y * vB.z, vB.z * H);
}

extern "C" void kernel_launch(void* const* d_in, const int* in_sizes, int n_in,
                              void* d_out, int out_size, void* d_ws, size_t ws_size,
                              hipStream_t stream) {
  const float* context  = (const float*)d_in[0];
  const float* question = (const float*)d_in[1];
  const int*   mask     = (const int*)d_in[2];
  const float* att_w    = (const float*)d_in[3];
  const float* att_b    = (const float*)d_in[4];
  const float* w_in     = (const float*)d_in[5];
  const float* w_mem    = (const float*)d_in[6];
  float4* out4 = (float4*)d_out;
  float4* ws4  = (float4*)d_ws;
  int*    cnt  = (int*)((char*)d_ws + CNT_OFF);

  // zero the 8 per-batch arrival counters (graph-capturable, poison-independent)
  hipMemsetAsync(cnt, 0, NB * sizeof(int), stream);

  fused_kernel<<<dim3(NB * BPB), dim3(TPB), 0, stream>>>(
      context, question, mask, att_w, att_b, w_in, w_mem, ws4, cnt, out4);
}